// Round 11
// baseline (3641.758 us; speedup 1.0000x reference)
//
#include <hip/hip_runtime.h>
#include <stdint.h>

typedef uint32_t u32;
typedef __bf16 bf16;
typedef bf16 bf16x8 __attribute__((ext_vector_type(8)));
typedef float f32x4 __attribute__((ext_vector_type(4)));

#define B_ 256
#define T_ 256
#define H_ 1024
#define G_ 4096   // 4*H
#define NI_ 2048

// ---- workspace layout ----
static constexpr size_t OFF_W2T = 0;                            // 16 MB  [2][4096 vcg][1024 k] bf16
static constexpr size_t SZ_W2T  = (size_t)2 * G_ * H_ * 2;
static constexpr size_t OFF_LENS= OFF_W2T + SZ_W2T;             // 1 KB
static constexpr size_t OFF_RL  = OFF_LENS + 1024;              // 1 KB
static constexpr size_t OFF_BAR = OFF_RL + 1024;                // 4 KB flags: [d][m][128] u32
static constexpr size_t SZ_BAR  = 4096;
static constexpr size_t OFF_H   = OFF_BAR + SZ_BAR;             // hf: R slots, then hb: R slots
static constexpr size_t SZ_SLOT = (size_t)B_ * H_ * 2;          // 512 KB per dir per slot
static constexpr size_t SLOT_U16 = (size_t)B_ * H_;             // 262144

static constexpr int LDS_BYTES = 131072;   // 2 dirs x 32 vcols x 1024 k bf16, swizzled

__device__ __forceinline__ float bf2f(uint16_t b){ return __uint_as_float(((u32)b) << 16); }
__device__ __forceinline__ uint16_t f2bf(float f){
  u32 u = __float_as_uint(f);
  return (uint16_t)((u + 0x7fffu + ((u >> 16) & 1u)) >> 16);  // RNE
}
__device__ __forceinline__ float sigm(float x){ return 1.f / (1.f + __expf(-x)); }
__device__ __forceinline__ float tanh_(float x){ return 1.f - 2.f / (__expf(2.f * x) + 1.f); }

// threefry2x32, jax rotations
__device__ __forceinline__ void threefry(u32 k0, u32 k1, u32 x0, u32 x1, u32& o0, u32& o1){
  u32 ks2 = k0 ^ k1 ^ 0x1BD11BDAu;
  x0 += k0; x1 += k1;
#define TFR(r) { x0 += x1; x1 = (x1 << r) | (x1 >> (32 - r)); x1 ^= x0; }
  TFR(13) TFR(15) TFR(26) TFR(6)  x0 += k1;  x1 += ks2 + 1u;
  TFR(17) TFR(29) TFR(16) TFR(24) x0 += ks2; x1 += k0 + 2u;
  TFR(13) TFR(15) TFR(26) TFR(6)  x0 += k0;  x1 += k1 + 3u;
  TFR(17) TFR(29) TFR(16) TFR(24) x0 += k1;  x1 += ks2 + 4u;
  TFR(13) TFR(15) TFR(26) TFR(6)  x0 += ks2; x1 += k0 + 5u;
#undef TFR
  o0 = x0; o1 = x1;
}

__device__ __forceinline__ bool keep_mask(u32 idx){
  u32 o0, o1; threefry(0u, 42u, 0u, idx, o0, o1);
  return ((o0 ^ o1) & 0x80000000u) == 0u;
}

// ---- prep: Whh (1024, 4096) f32 -> w2t[d][vcg][k] bf16
// col = strip*1024 + hc -> vcg = (hc>>3)*32 + (strip&1)*16 + (strip>>1)*8 + (hc&7)
__global__ __launch_bounds__(256) void k_prep_w(const float* __restrict__ whh_f,
                                                const float* __restrict__ whh_b,
                                                uint16_t* __restrict__ w2t){
  int bid = blockIdx.x;
  int d  = bid >> 12;
  int r  = bid & 4095;
  int kt = r >> 7;
  int ct = r & 127;
  const float* W = d ? whh_b : whh_f;
  __shared__ float tile[32][33];
  int tid = threadIdx.x;
  int lr = tid >> 5, lc = tid & 31;
#pragma unroll
  for (int i = 0; i < 4; i++)
    tile[lr + i*8][lc] = W[(size_t)(kt*32 + lr + i*8) * G_ + ct*32 + lc];
  __syncthreads();
  int colLocal = tid >> 3, kseg = tid & 7;
  int col = ct*32 + colLocal;
  int strip = col >> 10;
  int hcol  = col & 1023;
  int vcg = (hcol >> 3)*32 + (strip & 1)*16 + (strip >> 1)*8 + (hcol & 7);
  size_t base = ((size_t)d * G_ + vcg) * H_ + kt*32 + kseg*4;
  u32 w0 = (u32)f2bf(tile[kseg*4+0][colLocal]) | ((u32)f2bf(tile[kseg*4+1][colLocal]) << 16);
  u32 w1 = (u32)f2bf(tile[kseg*4+2][colLocal]) | ((u32)f2bf(tile[kseg*4+3][colLocal]) << 16);
  uint2 v; v.x = w0; v.y = w1;
  *(uint2*)(w2t + base) = v;
}

// ---- init: zero hf/hb slot 0 + flags; block 256 computes lens
__global__ __launch_bounds__(256) void k_init(uint16_t* __restrict__ hfp,
                                              uint16_t* __restrict__ hbp,
                                              int* __restrict__ lens,
                                              u32* __restrict__ bar,
                                              const int* __restrict__ items){
  int bid = blockIdx.x, tid = threadIdx.x;
  if (bid == 256){
    int cnt = 0;
    for (int t = 0; t < T_; t++) cnt += (items[(size_t)tid * T_ + t] != 0) ? 1 : 0;
    lens[tid] = cnt;
    return;
  }
  size_t g = (size_t)(bid & 127) * 256 + tid;          // 32768 uint4 = 512 KB per dir
  uint16_t* hp = (bid < 128) ? hfp : hbp;
  ((uint4*)hp)[g] = make_uint4(0,0,0,0);
  if (bid == 0) ((uint4*)bar)[tid] = make_uint4(0,0,0,0);   // 4 KB
}

// ---- asm helpers ----
#define A_LOADC(dst, base, IMM) \
  asm volatile("global_load_dwordx4 %0, %1, off offset:%2 sc0 sc1" \
    : "=v"(dst) : "v"(base), "i"(IMM) : "memory")
#define A_LOADN(dst, base, IMM) \
  asm volatile("global_load_dwordx4 %0, %1, off offset:%2" \
    : "=v"(dst) : "v"(base), "i"(IMM) : "memory")
#define A_WAIT(N, r0, r1) \
  asm volatile("s_waitcnt vmcnt(%2)" : "+v"(r0), "+v"(r1) : "i"(N) : "memory")
#define AISS(j) { if constexpr (CACHED) { \
    A_LOADN(pre0[(j)%10], pA + (size_t)(j)*16384, 0); \
    A_LOADN(pre1[(j)%10], pA + (size_t)(j)*16384, 256); \
  } else { \
    A_LOADC(pre0[(j)%10], pA + (size_t)(j)*16384, 0); \
    A_LOADC(pre1[(j)%10], pA + (size_t)(j)*16384, 256); } }

#define KSTEP(kk) { \
  bf16x8 bb0 = *(const bf16x8*)(smemD +         qoff00 + (((kk)&1)?qd1:qd0) + (((kk)&30)<<6)); \
  bf16x8 bb1 = *(const bf16x8*)(smemD + 32768 + qoff00 + (((kk)&1)?qd1:qd0) + (((kk)&30)<<6)); \
  A_WAIT(((kk)<=21 ? 18 : 62-2*(kk)), pre0[(kk)%10], pre1[(kk)%10]); \
  bf16x8 a0_ = pre0[(kk)%10]; bf16x8 a1_ = pre1[(kk)%10]; \
  accT0[0] = __builtin_amdgcn_mfma_f32_16x16x32_bf16(a0_, bb0, accT0[0], 0,0,0); \
  accT0[1] = __builtin_amdgcn_mfma_f32_16x16x32_bf16(a1_, bb0, accT0[1], 0,0,0); \
  accT1[0] = __builtin_amdgcn_mfma_f32_16x16x32_bf16(a0_, bb1, accT1[0], 0,0,0); \
  accT1[1] = __builtin_amdgcn_mfma_f32_16x16x32_bf16(a1_, bb1, accT1[1], 0,0,0); \
  if ((kk) < 22) { AISS((kk)+10); } }

#define R2(M,a)  M(a) M((a)+1)
#define R4(M,a)  M(a) M((a)+1) M((a)+2) M((a)+3)
#define R10(M,a) R4(M,a) R4(M,(a)+4) R2(M,(a)+8)
#define R16(M,a) R4(M,a) R4(M,(a)+4) R4(M,(a)+8) R4(M,(a)+12)

// one direction's step: acc-init, counted-vmcnt kloop, in-register epilogue, arrive.
#define DO_DIR(SMOFF, HINP, HOUTP, XG, XAV, ACV, TT, CREG, HREG, FOFF) \
  { \
    f32x4 accT0[2], accT1[2]; \
    _Pragma("unroll") for (int mi = 0; mi < 2; mi++) \
    _Pragma("unroll") for (int r4 = 0; r4 < 4; r4++){ \
      int i8 = mi*4 + r4; int a_ = ACV[i8]; \
      accT0[mi][r4] = XG[i8][0] + XAV[a_][0]; \
      accT1[mi][r4] = XG[i8][1] + XAV[a_][1]; } \
    asm volatile("s_waitcnt vmcnt(0)" ::: "memory"); \
    __builtin_amdgcn_sched_barrier(0); \
    const char* pA = (const char*)(HINP) + (size_t)(b0 + w*32 + c)*16 + (size_t)lk*4096; \
    const char* smemD = smem + (SMOFF); \
    R10(AISS, 0) \
    R16(KSTEP, 0) R16(KSTEP, 16) \
    __builtin_amdgcn_sched_barrier(0); \
    _Pragma("unroll") for (int mi = 0; mi < 2; mi++) \
    _Pragma("unroll") for (int r4 = 0; r4 < 4; r4++){ \
      int i8 = mi*4 + r4; \
      float u0 = accT0[mi][r4], u1 = accT1[mi][r4]; \
      float v0 = __shfl_xor(u0, 8, 64), v1 = __shfl_xor(u1, 8, 64); \
      float gi = chi ? v0 : u0; \
      float gf = chi ? v1 : u1; \
      float gg = chi ? u0 : v0; \
      float go = chi ? u1 : v1; \
      int row = b0 + w*32 + mi*16 + lk*4 + r4; \
      if ((TT) < len_r[i8]){ \
        float i_ = sigm(gi), f_ = sigm(gf), g_ = tanh_(gg), o_ = sigm(go); \
        float cn = f_ * CREG[i8] + i_ * g_; \
        CREG[i8] = cn; HREG[i8] = f2bf(o_ * tanh_(cn)); } \
      if (!chi){ \
        const uint16_t* addr_ = (HOUTP) + (size_t)n*2048 + (size_t)row*8 + hc8; \
        u32 hv_ = HREG[i8]; \
        asm volatile("global_store_short %0, %1, off sc0 sc1" :: "v"(addr_), "v"(hv_) : "memory"); } \
    } \
    asm volatile("s_waitcnt vmcnt(0)" ::: "memory"); \
  } \
  __syncthreads(); \
  if (tid == 0) __hip_atomic_store(bar + (FOFF) + n, (u32)(s+1), __ATOMIC_RELAXED, __HIP_MEMORY_SCOPE_AGENT);

#define WAITGRP(FOFF, TGT) do { \
  if (tid < 64){ \
    const u32 tgt_ = (u32)(TGT); \
    u32* fp_ = bar + (FOFF); \
    for(;;){ \
      u32 va_ = __hip_atomic_load(fp_ + tid,      __ATOMIC_RELAXED, __HIP_MEMORY_SCOPE_AGENT); \
      u32 vb_ = __hip_atomic_load(fp_ + tid + 64, __ATOMIC_RELAXED, __HIP_MEMORY_SCOPE_AGENT); \
      if (__all(va_ >= tgt_ && vb_ >= tgt_)) break; \
      __builtin_amdgcn_s_sleep(1); \
    } \
  } \
  __syncthreads(); \
} while(0)

// ---- persistent bidirectional LSTM. 256 blocks x 256 threads, cooperative launch.
// Block = (m: 128 rows, n: 8 hidden cols) x BOTH dirs. LDS = 2 x 32 vcols x 1024 k = 128 KB.
// Pipeline: kloop_f(s) -> arrive_f -> wait_b(s-1) -> kloop_b(s) -> arrive_b -> gathers -> wait_f(s).
// h layout per dir: [slot][n'=128][row=256][8 cols] bf16 (one writer block per 128B line).
template <bool CACHED>
__global__ __launch_bounds__(256, 1) void k_persist(
    const int* __restrict__ items, const int* __restrict__ actions,
    const float* __restrict__ wt_f, const float* __restrict__ wt_b,
    const float* __restrict__ bias_f, const float* __restrict__ bias_b,
    const uint16_t* __restrict__ w2t, uint16_t* __restrict__ hf, uint16_t* __restrict__ hb,
    const int* __restrict__ lens, u32* __restrict__ bar, int rmask)
{
  extern __shared__ char smem[];
  const int bid = blockIdx.x;
  // XCD swizzle: m=0 -> XCDs 0..3, m=1 -> XCDs 4..7
  const int m = (bid >> 2) & 1;
  const int n = (bid >> 3) * 4 + (bid & 3);       // 0..127
  const int tid = threadIdx.x;
  const int b0 = m * 128;

  // --- stage both dirs' weight slices -> LDS (XOR-swizzled along k) ---
#pragma unroll
  for (int dd = 0; dd < 2; dd++){
    const char* wsrc = (const char*)(w2t + ((size_t)dd * G_ + n*32) * H_);
#pragma unroll
    for (int i = 0; i < 16; i++){
      int u = i*256 + tid;              // 4096 x 16B = 64 KB
      int row = u >> 7, seg = u & 127;
      int sb = seg * 16;
      uint4 v = *(const uint4*)(wsrc + row*2048 + sb);
      *(uint4*)(smem + dd*65536 + row*2048 + (sb ^ ((row & 7) << 4))) = v;
    }
  }

  const int w   = tid >> 6;
  const int l   = tid & 63;
  const int c   = l & 15;
  const int lk  = l >> 4;
  const int hc8 = c & 7;
  const int chi = (c >> 3) & 1;    // 0: lane holds gates (i,f); 1: (g,o)
  // lane's two gate columns: tile0 = i or g, tile1 = f or o
  const int gcol0 = (chi ? 2 : 0)*1024 + n*8 + hc8;
  const int gcol1 = (chi ? 3 : 1)*1024 + n*8 + hc8;

  float xavf[3][2], xavb[3][2];
#pragma unroll
  for (int a = 0; a < 3; a++){
    xavf[a][0] = wt_f[(size_t)(NI_ + a) * G_ + gcol0] + bias_f[gcol0];
    xavf[a][1] = wt_f[(size_t)(NI_ + a) * G_ + gcol1] + bias_f[gcol1];
    xavb[a][0] = wt_b[(size_t)(NI_ + a) * G_ + gcol0] + bias_b[gcol0];
    xavb[a][1] = wt_b[(size_t)(NI_ + a) * G_ + gcol1] + bias_b[gcol1];
  }

  int len_r[8];
#pragma unroll
  for (int i = 0; i < 8; i++)
    len_r[i] = lens[b0 + w*32 + (i>>2)*16 + lk*4 + (i&3)];

  // --- initial gathers (t_f=0, t_b=T-1) ---
  int itf[8], acf[8], itb[8], acb[8];
  float xgf[8][2], xgb[8][2];
#pragma unroll
  for (int i = 0; i < 8; i++){
    int row = b0 + w*32 + (i>>2)*16 + lk*4 + (i&3);
    itf[i] = items[(size_t)row * T_ + 0];        acf[i] = actions[(size_t)row * T_ + 0];
    itb[i] = items[(size_t)row * T_ + (T_-1)];   acb[i] = actions[(size_t)row * T_ + (T_-1)];
  }
#pragma unroll
  for (int i = 0; i < 8; i++){
    xgf[i][0] = wt_f[(size_t)itf[i] * G_ + gcol0]; xgf[i][1] = wt_f[(size_t)itf[i] * G_ + gcol1];
    xgb[i][0] = wt_b[(size_t)itb[i] * G_ + gcol0]; xgb[i][1] = wt_b[(size_t)itb[i] * G_ + gcol1];
  }

  // LDS b-read offset pieces (same swizzle algebra as prior rounds)
  const int key  = (c & 7) << 4;
  const int kbit = (c >> 2) & 1;
  const u32 qoff00 = (u32)(c*2048 + ((lk*16) ^ (key & 48)));
  const u32 qd0 = (u32)((kbit) << 6);
  const u32 qd1 = (u32)((1 ^ kbit) << 6);

  float crf[8], crb[8]; uint16_t hrf[8], hrb[8];
#pragma unroll
  for (int i = 0; i < 8; i++){ crf[i] = 0.f; crb[i] = 0.f; hrf[i] = 0; hrb[i] = 0; }

  __syncthreads();   // W LDS ready

  bf16x8 pre0[10], pre1[10];

  for (int s = 0; s < T_; s++){
    if (CACHED && s != 0 && ((s & rmask) == 0))
      __builtin_amdgcn_fence(__ATOMIC_ACQUIRE, "agent");

    const int tf = s, tb = T_-1-s;
    const uint16_t* hfin  = hf + (size_t)(s & rmask) * SLOT_U16;
    uint16_t*       hfout = hf + (size_t)((s+1) & rmask) * SLOT_U16;
    const uint16_t* hbin  = hb + (size_t)(s & rmask) * SLOT_U16;
    uint16_t*       hbout = hb + (size_t)((s+1) & rmask) * SLOT_U16;

    // ---- forward ----
    DO_DIR(0, hfin, hfout, xgf, xavf, acf, tf, crf, hrf, m*128)
    // ---- wait for backward step s-1 (hidden behind kloop_f) ----
    if (s) { WAITGRP(256 + m*128, (u32)s); }
    // ---- backward ----
    DO_DIR(65536, hbin, hbout, xgb, xavb, acb, tb, crb, hrb, 256 + m*128)
    if (s == T_-1) break;

    // ---- tail window: gathers for step s+1 (hide under wait_f) ----
    {
      int tf2 = s + 1, tb2 = T_ - 2 - s;
#pragma unroll
      for (int i = 0; i < 8; i++){
        int row = b0 + w*32 + (i>>2)*16 + lk*4 + (i&3);
        itf[i] = items[(size_t)row * T_ + tf2]; acf[i] = actions[(size_t)row * T_ + tf2];
        itb[i] = items[(size_t)row * T_ + tb2]; acb[i] = actions[(size_t)row * T_ + tb2];
      }
#pragma unroll
      for (int i = 0; i < 8; i++){
        xgf[i][0] = wt_f[(size_t)itf[i] * G_ + gcol0]; xgf[i][1] = wt_f[(size_t)itf[i] * G_ + gcol1];
        xgb[i][0] = wt_b[(size_t)itb[i] * G_ + gcol0]; xgb[i][1] = wt_b[(size_t)itb[i] * G_ + gcol1];
      }
    }
    // ---- wait for forward step s (hidden behind kloop_b + gathers) ----
    WAITGRP(m*128, (u32)(s+1));
  }
}

// ---- FC + per-row loss (h layout per dir: [n'=128][256][8]) ----
__global__ __launch_bounds__(256) void k_fc(const uint16_t* __restrict__ hfq,
    const uint16_t* __restrict__ hbq,
    const float* __restrict__ wfc, const float* __restrict__ bfc,
    const int* __restrict__ targets, float* __restrict__ rowloss){
  int b = blockIdx.x, tid = threadIdx.x;
  float a0 = 0.f, a1 = 0.f;
  for (int jj = tid; jj < 2*H_; jj += 256){
    int d = jj >> 10, j = jj & 1023;
    const uint16_t* hp = d ? hbq : hfq;
    float h = bf2f(hp[(size_t)(j >> 3) * 2048 + (size_t)b * 8 + (j & 7)]);
    u32 idx = (u32)(d * (B_ * H_) + b * H_ + j);     // logical (2,B,H) index for dropout
    float feat = keep_mask(idx) ? (2.f * h) : 0.f;
    a0 += feat * wfc[jj*2 + 0];
    a1 += feat * wfc[jj*2 + 1];
  }
#pragma unroll
  for (int off = 32; off > 0; off >>= 1){
    a0 += __shfl_down(a0, off, 64);
    a1 += __shfl_down(a1, off, 64);
  }
  __shared__ float r0[4], r1[4];
  if ((tid & 63) == 0){ r0[tid >> 6] = a0; r1[tid >> 6] = a1; }
  __syncthreads();
  if (tid == 0){
    float l0 = r0[0]+r0[1]+r0[2]+r0[3] + bfc[0];
    float l1 = r1[0]+r1[1]+r1[2]+r1[3] + bfc[1];
    float mx = fmaxf(l0, l1);
    float lse = mx + logf(__expf(l0 - mx) + __expf(l1 - mx));
    rowloss[b] = lse - (targets[b] ? l1 : l0);
  }
}

__global__ __launch_bounds__(256) void k_loss(const float* __restrict__ rowloss, float* __restrict__ out){
  int tid = threadIdx.x;
  float v = rowloss[tid];
#pragma unroll
  for (int off = 32; off > 0; off >>= 1) v += __shfl_down(v, off, 64);
  __shared__ float r[4];
  if ((tid & 63) == 0) r[tid >> 6] = v;
  __syncthreads();
  if (tid == 0) out[0] = (r[0] + r[1] + r[2] + r[3]) * (1.f / B_);
}

extern "C" void kernel_launch(void* const* d_in, const int* in_sizes, int n_in,
                              void* d_out, int out_size, void* d_ws, size_t ws_size,
                              hipStream_t stream){
  (void)in_sizes; (void)n_in; (void)out_size;
  const int*   items   = (const int*)  d_in[0];
  const int*   actions = (const int*)  d_in[1];
  const int*   targets = (const int*)  d_in[2];
  const float* wt_f    = (const float*)d_in[3];
  const float* whh_f   = (const float*)d_in[4];
  const float* b_f     = (const float*)d_in[5];
  const float* wt_b    = (const float*)d_in[6];
  const float* whh_b   = (const float*)d_in[7];
  const float* b_b     = (const float*)d_in[8];
  const float* wfc     = (const float*)d_in[9];
  const float* bfc     = (const float*)d_in[10];

  char* ws = (char*)d_ws;
  uint16_t* w2t   = (uint16_t*)(ws + OFF_W2T);
  int*      lens  = (int*)     (ws + OFF_LENS);
  float*    rlbuf = (float*)   (ws + OFF_RL);
  u32*      bar   = (u32*)     (ws + OFF_BAR);
  uint16_t* hf    = (uint16_t*)(ws + OFF_H);

  // rotation depth gated by workspace size (2 dirs x R x 512 KB)
  int R = 0;
  if      (ws_size >= OFF_H + 32u * SZ_SLOT) R = 16;
  else if (ws_size >= OFF_H + 16u * SZ_SLOT) R = 8;
  else if (ws_size >= OFF_H +  8u * SZ_SLOT) R = 4;
  int rmask = R ? (R - 1) : 1;
  int Reff  = R ? R : 2;
  uint16_t* hb = hf + (size_t)Reff * SLOT_U16;

  hipFuncSetAttribute((const void*)k_persist<true>,
                      hipFuncAttributeMaxDynamicSharedMemorySize, LDS_BYTES);
  hipFuncSetAttribute((const void*)k_persist<false>,
                      hipFuncAttributeMaxDynamicSharedMemorySize, LDS_BYTES);

  hipLaunchKernelGGL(k_prep_w, dim3(8192), dim3(256), 0, stream, whh_f, whh_b, w2t);
  hipLaunchKernelGGL(k_init,   dim3(257),  dim3(256), 0, stream, hf, hb, lens, bar, items);

  void* args[] = { (void*)&items, (void*)&actions, (void*)&wt_f, (void*)&wt_b,
                   (void*)&b_f, (void*)&b_b, (void*)&w2t, (void*)&hf, (void*)&hb,
                   (void*)&lens, (void*)&bar, (void*)&rmask };
  if (R)
    hipLaunchCooperativeKernel((const void*)k_persist<true>, dim3(256), dim3(256),
                               args, LDS_BYTES, stream);
  else
    hipLaunchCooperativeKernel((const void*)k_persist<false>, dim3(256), dim3(256),
                               args, LDS_BYTES, stream);

  // final h is slot 0 of each dir (256 ≡ 0 mod R)
  hipLaunchKernelGGL(k_fc,   dim3(256), dim3(256), 0, stream, hf, hb, wfc, bfc, targets, rlbuf);
  hipLaunchKernelGGL(k_loss, dim3(1),   dim3(256), 0, stream, rlbuf, (float*)d_out);
}